// Round 1
// baseline (643.567 us; speedup 1.0000x reference)
//
#include <hip/hip_runtime.h>
#include <cstdint>

#define N_EMB 6272      // B*W*H = 8*28*28
#define DIMD  128
#define M_BANK 16384
#define BATCH 8
#define PPB   784       // patches per batch
#define KNN   9
#define EPSF  1e-12f

#define BN 64
#define BM 64
#define BK 32

typedef unsigned long long u64;

static __device__ __forceinline__ u64 umin64(u64 a, u64 b) { return b < a ? b : a; }
static __device__ __forceinline__ u64 umax64(u64 a, u64 b) { return b > a ? b : a; }

// ---------------- Phase A: row squared-norms ----------------
// 8 rows per block; 32 threads per row, each loads one float4 (coalesced).
__global__ void rownorm_kernel(const float* __restrict__ emb,
                               const float* __restrict__ bank,
                               float* __restrict__ x2,
                               float* __restrict__ y2) {
    int rid  = blockIdx.x * 8 + (threadIdx.x >> 5);
    int lane = threadIdx.x & 31;
    const float* src;
    float* dst;
    int idx;
    if (rid < M_BANK) {
        src = bank + (size_t)rid * DIMD; dst = y2; idx = rid;
    } else {
        idx = rid - M_BANK;
        if (idx >= N_EMB) return;
        src = emb + (size_t)idx * DIMD; dst = x2;
    }
    float4 v = ((const float4*)src)[lane];
    float s = v.x*v.x + v.y*v.y + v.z*v.z + v.w*v.w;
    #pragma unroll
    for (int off = 16; off; off >>= 1) s += __shfl_down(s, off, 32);
    if (lane == 0) dst[idx] = s;
}

// ---------------- Phase B: tiled dist^2 + per-row min/argmin ----------------
// grid (M_BANK/BM, N_EMB/BN), 256 threads, 4x4 register blocking.
__global__ __launch_bounds__(256) void dist_min_kernel(
        const float* __restrict__ emb, const float* __restrict__ bank,
        const float* __restrict__ x2, const float* __restrict__ y2,
        u64* __restrict__ packed) {
    __shared__ float As[BK][BN + 4];
    __shared__ float Bs[BK][BM + 4];

    const int n0 = blockIdx.y * BN;
    const int m0 = blockIdx.x * BM;
    const int tid = threadIdx.x;
    const int tx = tid & 15;        // m sub-tile
    const int ty = tid >> 4;        // n sub-tile

    const int lr = tid >> 3;        // 0..31  (row within tile; also handles lr+32)
    const int lc = (tid & 7) * 4;   // 0,4,...,28 (k within BK chunk)

    float acc[4][4] = {};

    for (int k0 = 0; k0 < DIMD; k0 += BK) {
        float4 a0 = *(const float4*)(emb  + (size_t)(n0 + lr)      * DIMD + k0 + lc);
        float4 a1 = *(const float4*)(emb  + (size_t)(n0 + lr + 32) * DIMD + k0 + lc);
        float4 b0 = *(const float4*)(bank + (size_t)(m0 + lr)      * DIMD + k0 + lc);
        float4 b1 = *(const float4*)(bank + (size_t)(m0 + lr + 32) * DIMD + k0 + lc);
        __syncthreads();   // protect previous iteration's tile reads
        As[lc+0][lr]    = a0.x; As[lc+1][lr]    = a0.y; As[lc+2][lr]    = a0.z; As[lc+3][lr]    = a0.w;
        As[lc+0][lr+32] = a1.x; As[lc+1][lr+32] = a1.y; As[lc+2][lr+32] = a1.z; As[lc+3][lr+32] = a1.w;
        Bs[lc+0][lr]    = b0.x; Bs[lc+1][lr]    = b0.y; Bs[lc+2][lr]    = b0.z; Bs[lc+3][lr]    = b0.w;
        Bs[lc+0][lr+32] = b1.x; Bs[lc+1][lr+32] = b1.y; Bs[lc+2][lr+32] = b1.z; Bs[lc+3][lr+32] = b1.w;
        __syncthreads();
        #pragma unroll
        for (int kk = 0; kk < BK; ++kk) {
            float av[4], bv[4];
            *(float4*)av = *(const float4*)&As[kk][ty * 4];
            *(float4*)bv = *(const float4*)&Bs[kk][tx * 4];
            #pragma unroll
            for (int i = 0; i < 4; ++i)
                #pragma unroll
                for (int j = 0; j < 4; ++j)
                    acc[i][j] += av[i] * bv[j];
        }
    }

    float ys[4];
    #pragma unroll
    for (int j = 0; j < 4; ++j) ys[j] = y2[m0 + tx * 4 + j];

    #pragma unroll
    for (int i = 0; i < 4; ++i) {
        const int n = n0 + ty * 4 + i;
        const float xs = x2[n];
        u64 best = ~0ull;
        #pragma unroll
        for (int j = 0; j < 4; ++j) {
            const int m = m0 + tx * 4 + j;
            float d2 = xs + ys[j] - 2.0f * acc[i][j];
            d2 = fmaxf(d2, EPSF);
            u64 key = ((u64)__float_as_uint(d2) << 32) | (unsigned)m;
            best = umin64(best, key);
        }
        // reduce across the 16 tx-lanes (consecutive lanes within one wave)
        #pragma unroll
        for (int off = 8; off; off >>= 1)
            best = umin64(best, (u64)__shfl_down((unsigned long long)best, off, 16));
        if (tx == 0) atomicMin(&packed[n], best);
    }
}

// ---------------- Phase C1: per-batch argmax of patch score ----------------
__global__ void argmax_kernel(const u64* __restrict__ packed,
                              uint4* __restrict__ binfo) {
    const int b = blockIdx.x, tid = threadIdx.x;
    __shared__ u64 red[256];
    u64 bk = 0;
    for (int p = tid; p < PPB; p += 256) {
        u64 pk = packed[(size_t)b * PPB + p];
        unsigned d2b = (unsigned)(pk >> 32);
        // prefer larger d2; tie -> smaller p (matches jnp.argmax first-occurrence)
        u64 key = ((u64)d2b << 32) | (u64)(0xFFFFFFFFu - (unsigned)p);
        bk = umax64(bk, key);
    }
    red[tid] = bk; __syncthreads();
    for (int s = 128; s; s >>= 1) {
        if (tid < s) red[tid] = umax64(red[tid], red[tid + s]);
        __syncthreads();
    }
    if (tid == 0) {
        u64 w = red[0];
        unsigned p   = 0xFFFFFFFFu - (unsigned)w;
        unsigned d2b = (unsigned)(w >> 32);
        unsigned nn  = (unsigned)packed[(size_t)b * PPB + p];
        binfo[b] = make_uint4(p, nn, d2b, 0u);
    }
}

// ---------------- Phase C2: dist^2(nn_sample, bank) ----------------
// grid (M_BANK/256, BATCH)
__global__ void dnn_kernel(const float* __restrict__ bank,
                           const float* __restrict__ y2,
                           const uint4* __restrict__ binfo,
                           float* __restrict__ dnn) {
    const int b = blockIdx.y;
    const unsigned nn = binfo[b].y;
    __shared__ float nv[DIMD];
    if (threadIdx.x < DIMD) nv[threadIdx.x] = bank[(size_t)nn * DIMD + threadIdx.x];
    __syncthreads();
    const int m = blockIdx.x * 256 + threadIdx.x;
    const float4* row = (const float4*)(bank + (size_t)m * DIMD);
    float dot = 0.f;
    #pragma unroll
    for (int q = 0; q < DIMD / 4; ++q) {
        float4 v = row[q];
        dot += v.x * nv[q*4+0] + v.y * nv[q*4+1] + v.z * nv[q*4+2] + v.w * nv[q*4+3];
    }
    float d2 = y2[nn] + y2[m] - 2.0f * dot;
    dnn[(size_t)b * M_BANK + m] = fmaxf(d2, EPSF);
}

// ---------------- Phase C3: top-9, final distances, softmax, output ----------------
__global__ void final_kernel(const float* __restrict__ emb,
                             const float* __restrict__ bank,
                             const float* __restrict__ x2,
                             const float* __restrict__ y2,
                             const uint4* __restrict__ binfo,
                             const float* __restrict__ dnn,
                             float* __restrict__ out) {
    const int b = blockIdx.x, tid = threadIdx.x;
    __shared__ u64 red[256];
    __shared__ unsigned s_sup[KNN];
    __shared__ float s_dist[KNN];
    __shared__ float xv[DIMD];

    uint4 info = binfo[b];
    const unsigned nstar = info.x;
    const float d2star = __uint_as_float(info.z);
    if (tid < DIMD) xv[tid] = emb[(size_t)(b * PPB + nstar) * DIMD + tid];
    __syncthreads();

    for (int r = 0; r < KNN; ++r) {
        u64 bk = ~0ull;
        for (int m = tid; m < M_BANK; m += 256) {
            bool skip = false;
            for (int rr = 0; rr < r; ++rr) if (s_sup[rr] == (unsigned)m) skip = true;
            if (!skip) {
                float v = dnn[(size_t)b * M_BANK + m];
                u64 key = ((u64)__float_as_uint(v) << 32) | (unsigned)m;
                bk = umin64(bk, key);
            }
        }
        red[tid] = bk; __syncthreads();
        for (int s = 128; s; s >>= 1) {
            if (tid < s) red[tid] = umin64(red[tid], red[tid + s]);
            __syncthreads();
        }
        if (tid == 0) s_sup[r] = (unsigned)red[0];
        __syncthreads();
    }

    if (tid < KNN) {
        const unsigned s = s_sup[tid];
        const float* srow = bank + (size_t)s * DIMD;
        float dot = 0.f;
        for (int d = 0; d < DIMD; ++d) dot += srow[d] * xv[d];
        float d2 = x2[b * PPB + nstar] + y2[s] - 2.0f * dot;
        s_dist[tid] = sqrtf(fmaxf(d2, EPSF));
    }
    __syncthreads();

    if (tid == 0) {
        float mx = s_dist[0];
        for (int i = 1; i < KNN; ++i) mx = fmaxf(mx, s_dist[i]);
        float sum = 0.f, e0 = 0.f;
        for (int i = 0; i < KNN; ++i) {
            float e = expf(s_dist[i] - mx);
            sum += e;
            if (i == 0) e0 = e;
        }
        float w = 1.0f - e0 / sum;
        out[b] = w * sqrtf(fmaxf(d2star, EPSF));
    }
}

extern "C" void kernel_launch(void* const* d_in, const int* in_sizes, int n_in,
                              void* d_out, int out_size, void* d_ws, size_t ws_size,
                              hipStream_t stream) {
    const float* emb  = (const float*)d_in[0];
    const float* bank = (const float*)d_in[1];
    float* out = (float*)d_out;

    char* ws = (char*)d_ws;
    u64*   packed = (u64*)   (ws + 0);        //  50176 B
    float* x2     = (float*) (ws + 65536);    //  25088 B
    float* y2     = (float*) (ws + 131072);   //  65536 B
    uint4* binfo  = (uint4*) (ws + 200704);   //    128 B
    float* dnn    = (float*) (ws + 262144);   // 524288 B

    hipMemsetAsync(packed, 0xFF, (size_t)N_EMB * sizeof(u64), stream);

    {
        int rows = M_BANK + N_EMB;               // 22656
        int blocks = (rows + 7) / 8;             // 2832
        rownorm_kernel<<<blocks, 256, 0, stream>>>(emb, bank, x2, y2);
    }

    dist_min_kernel<<<dim3(M_BANK / BM, N_EMB / BN), 256, 0, stream>>>(
        emb, bank, x2, y2, packed);

    argmax_kernel<<<BATCH, 256, 0, stream>>>(packed, binfo);

    dnn_kernel<<<dim3(M_BANK / 256, BATCH), 256, 0, stream>>>(bank, y2, binfo, dnn);

    final_kernel<<<BATCH, 256, 0, stream>>>(emb, bank, x2, y2, binfo, dnn, out);
}

// Round 2
// 347.917 us; speedup vs baseline: 1.8498x; 1.8498x over previous
//
#include <hip/hip_runtime.h>
#include <cstdint>

#define N_EMB 6272      // B*W*H = 8*28*28
#define DIMD  128
#define M_BANK 16384
#define BATCH 8
#define PPB   784       // patches per batch
#define KNN   9
#define EPSF  1e-12f

typedef unsigned long long u64;
typedef _Float16 f16x8 __attribute__((ext_vector_type(8)));
typedef float    f32x4 __attribute__((ext_vector_type(4)));

static __device__ __forceinline__ u64 umin64(u64 a, u64 b) { return b < a ? b : a; }
static __device__ __forceinline__ u64 umax64(u64 a, u64 b) { return b > a ? b : a; }

// swizzled element index in a [128][64] fp16 LDS tile (row stride 128 B).
// byte = row*128 + col*2 ; swizzle byte ^= (row&7)<<4  ->  elem ^= (row&7)<<3
#define SWZ(row, col) ((((row) << 6) + (col)) ^ (((row) & 7) << 3))

// ---------------- Phase A: row squared-norms (fp32 exact) ----------------
__global__ void rownorm_kernel(const float* __restrict__ emb,
                               const float* __restrict__ bank,
                               float* __restrict__ x2,
                               float* __restrict__ y2) {
    int rid  = blockIdx.x * 8 + (threadIdx.x >> 5);
    int lane = threadIdx.x & 31;
    const float* src;
    float* dst;
    int idx;
    if (rid < M_BANK) {
        src = bank + (size_t)rid * DIMD; dst = y2; idx = rid;
    } else {
        idx = rid - M_BANK;
        if (idx >= N_EMB) return;
        src = emb + (size_t)idx * DIMD; dst = x2;
    }
    float4 v = ((const float4*)src)[lane];
    float s = v.x*v.x + v.y*v.y + v.z*v.z + v.w*v.w;
    #pragma unroll
    for (int off = 16; off; off >>= 1) s += __shfl_down(s, off, 32);
    if (lane == 0) dst[idx] = s;
}

// ---------------- Phase B: MFMA dist^2 + per-row min/argmin ----------------
// grid (N_EMB/128, M_BANK/128), 256 threads (4 waves, each a 64x64 quadrant).
// fp16 hi/lo split: dot = hi*hi + hi*lo + lo*hi  (error ~2e-5 in d2).
static __device__ __forceinline__ void cvt8(float4 v0, float4 v1,
                                            f16x8* hi, f16x8* lo) {
    float f[8] = {v0.x, v0.y, v0.z, v0.w, v1.x, v1.y, v1.z, v1.w};
    #pragma unroll
    for (int i = 0; i < 8; ++i) {
        _Float16 h = (_Float16)f[i];
        (*hi)[i] = h;
        (*lo)[i] = (_Float16)(f[i] - (float)h);
    }
}

__global__ __launch_bounds__(256) void dist_min_mfma(
        const float* __restrict__ emb, const float* __restrict__ bank,
        const float* __restrict__ x2, const float* __restrict__ y2,
        u64* __restrict__ packed) {
    __shared__ _Float16 sAhi[128 * 64];
    __shared__ _Float16 sAlo[128 * 64];
    __shared__ _Float16 sBhi[128 * 64];
    __shared__ _Float16 sBlo[128 * 64];

    const int n0 = blockIdx.x * 128;   // emb rows
    const int m0 = blockIdx.y * 128;   // bank rows
    const int tid  = threadIdx.x;
    const int lane = tid & 63;
    const int wid  = tid >> 6;
    const int wn = wid >> 1;           // 0..1: emb-quadrant
    const int wm = wid & 1;            // 0..1: bank-quadrant

    const int srow = tid >> 1;         // staging row 0..127
    const int sseg = (tid & 1) * 32;   // staging float offset within 64-chunk

    f32x4 acc[4][4] = {};

    #pragma unroll
    for (int p = 0; p < 2; ++p) {
        if (p) __syncthreads();        // previous phase's reads done
        // ---- stage A (emb) and B (bank), fp32 -> hi/lo fp16, swizzled ----
        {
            const float* srcA = emb  + (size_t)(n0 + srow) * DIMD + p * 64 + sseg;
            const float* srcB = bank + (size_t)(m0 + srow) * DIMD + p * 64 + sseg;
            #pragma unroll
            for (int it = 0; it < 4; ++it) {
                float4 a0 = ((const float4*)srcA)[it * 2];
                float4 a1 = ((const float4*)srcA)[it * 2 + 1];
                float4 b0 = ((const float4*)srcB)[it * 2];
                float4 b1 = ((const float4*)srcB)[it * 2 + 1];
                f16x8 ah, al, bh, bl;
                cvt8(a0, a1, &ah, &al);
                cvt8(b0, b1, &bh, &bl);
                int col = sseg + it * 8;
                int idx = SWZ(srow, col);
                *(f16x8*)&sAhi[idx] = ah;
                *(f16x8*)&sAlo[idx] = al;
                *(f16x8*)&sBhi[idx] = bh;
                *(f16x8*)&sBlo[idx] = bl;
            }
        }
        __syncthreads();
        // ---- compute: 2 k-steps of 32 within this 64-wide phase ----
        #pragma unroll
        for (int ks = 0; ks < 2; ++ks) {
            const int kofs = ks * 32 + (lane >> 4) * 8;
            f16x8 ah[4], al[4], bh[4], bl[4];
            #pragma unroll
            for (int f = 0; f < 4; ++f) {
                int arow = wn * 64 + f * 16 + (lane & 15);
                int aidx = SWZ(arow, kofs);
                ah[f] = *(const f16x8*)&sAhi[aidx];
                al[f] = *(const f16x8*)&sAlo[aidx];
                int brow = wm * 64 + f * 16 + (lane & 15);
                int bidx = SWZ(brow, kofs);
                bh[f] = *(const f16x8*)&sBhi[bidx];
                bl[f] = *(const f16x8*)&sBlo[bidx];
            }
            #pragma unroll
            for (int i = 0; i < 4; ++i)
                #pragma unroll
                for (int j = 0; j < 4; ++j) {
                    acc[i][j] = __builtin_amdgcn_mfma_f32_16x16x32_f16(ah[i], bh[j], acc[i][j], 0, 0, 0);
                    acc[i][j] = __builtin_amdgcn_mfma_f32_16x16x32_f16(ah[i], bl[j], acc[i][j], 0, 0, 0);
                    acc[i][j] = __builtin_amdgcn_mfma_f32_16x16x32_f16(al[i], bh[j], acc[i][j], 0, 0, 0);
                }
        }
    }

    // ---- epilogue: d2 = x2 + y2 - 2*dot, pack, reduce, atomicMin ----
    float ys[4];
    #pragma unroll
    for (int j = 0; j < 4; ++j)
        ys[j] = y2[m0 + wm * 64 + j * 16 + (lane & 15)];

    #pragma unroll
    for (int fi = 0; fi < 4; ++fi) {
        #pragma unroll
        for (int r = 0; r < 4; ++r) {
            const int n = n0 + wn * 64 + fi * 16 + (lane >> 4) * 4 + r;
            const float xs = x2[n];
            u64 best = ~0ull;
            #pragma unroll
            for (int fj = 0; fj < 4; ++fj) {
                const int m = m0 + wm * 64 + fj * 16 + (lane & 15);
                float d2 = xs + ys[fj] - 2.0f * acc[fi][fj][r];
                d2 = fmaxf(d2, EPSF);
                u64 key = ((u64)__float_as_uint(d2) << 32) | (unsigned)m;
                best = umin64(best, key);
            }
            #pragma unroll
            for (int off = 1; off < 16; off <<= 1)
                best = umin64(best, (u64)__shfl_xor((unsigned long long)best, off));
            if ((lane & 15) == 0) atomicMin(&packed[n], best);
        }
    }
}

// ---------------- Phase C1: per-batch argmax of patch score ----------------
__global__ void argmax_kernel(const u64* __restrict__ packed,
                              uint4* __restrict__ binfo) {
    const int b = blockIdx.x, tid = threadIdx.x;
    __shared__ u64 red[256];
    u64 bk = 0;
    for (int p = tid; p < PPB; p += 256) {
        u64 pk = packed[(size_t)b * PPB + p];
        unsigned d2b = (unsigned)(pk >> 32);
        u64 key = ((u64)d2b << 32) | (u64)(0xFFFFFFFFu - (unsigned)p);
        bk = umax64(bk, key);
    }
    red[tid] = bk; __syncthreads();
    for (int s = 128; s; s >>= 1) {
        if (tid < s) red[tid] = umax64(red[tid], red[tid + s]);
        __syncthreads();
    }
    if (tid == 0) {
        u64 w = red[0];
        unsigned p   = 0xFFFFFFFFu - (unsigned)w;
        unsigned d2b = (unsigned)(w >> 32);
        unsigned nn  = (unsigned)packed[(size_t)b * PPB + p];
        binfo[b] = make_uint4(p, nn, d2b, 0u);
    }
}

// ---------------- Phase C2: dist^2(nn_sample, bank) ----------------
__global__ void dnn_kernel(const float* __restrict__ bank,
                           const float* __restrict__ y2,
                           const uint4* __restrict__ binfo,
                           float* __restrict__ dnn) {
    const int b = blockIdx.y;
    const unsigned nn = binfo[b].y;
    __shared__ float nv[DIMD];
    if (threadIdx.x < DIMD) nv[threadIdx.x] = bank[(size_t)nn * DIMD + threadIdx.x];
    __syncthreads();
    const int m = blockIdx.x * 256 + threadIdx.x;
    const float4* row = (const float4*)(bank + (size_t)m * DIMD);
    float dot = 0.f;
    #pragma unroll
    for (int q = 0; q < DIMD / 4; ++q) {
        float4 v = row[q];
        dot += v.x * nv[q*4+0] + v.y * nv[q*4+1] + v.z * nv[q*4+2] + v.w * nv[q*4+3];
    }
    float d2 = y2[nn] + y2[m] - 2.0f * dot;
    dnn[(size_t)b * M_BANK + m] = fmaxf(d2, EPSF);
}

// ---------------- Phase C3: top-9, final distances, softmax, output --------
__global__ void final_kernel(const float* __restrict__ emb,
                             const float* __restrict__ bank,
                             const float* __restrict__ x2,
                             const float* __restrict__ y2,
                             const uint4* __restrict__ binfo,
                             float* __restrict__ dnn,
                             float* __restrict__ out) {
    const int b = blockIdx.x, tid = threadIdx.x;
    __shared__ u64 red[256];
    __shared__ unsigned s_sup[KNN];
    __shared__ float s_dist[KNN];
    __shared__ float xv[DIMD];

    uint4 info = binfo[b];
    const unsigned nstar = info.x;
    const float d2star = __uint_as_float(info.z);
    if (tid < DIMD) xv[tid] = emb[(size_t)(b * PPB + nstar) * DIMD + tid];
    __syncthreads();

    for (int r = 0; r < KNN; ++r) {
        u64 bk = ~0ull;
        for (int m = tid; m < M_BANK; m += 256) {
            float v = dnn[(size_t)b * M_BANK + m];
            u64 key = ((u64)__float_as_uint(v) << 32) | (unsigned)m;
            bk = umin64(bk, key);
        }
        red[tid] = bk; __syncthreads();
        for (int s = 128; s; s >>= 1) {
            if (tid < s) red[tid] = umin64(red[tid], red[tid + s]);
            __syncthreads();
        }
        if (tid == 0) {
            unsigned sel = (unsigned)red[0];
            s_sup[r] = sel;
            dnn[(size_t)b * M_BANK + sel] = 1e30f;  // exclude from later rounds
        }
        __syncthreads();
    }

    if (tid < KNN) {
        const unsigned s = s_sup[tid];
        const float* srow = bank + (size_t)s * DIMD;
        float dot = 0.f;
        for (int d = 0; d < DIMD; ++d) dot += srow[d] * xv[d];
        float d2 = x2[b * PPB + nstar] + y2[s] - 2.0f * dot;
        s_dist[tid] = sqrtf(fmaxf(d2, EPSF));
    }
    __syncthreads();

    if (tid == 0) {
        float mx = s_dist[0];
        for (int i = 1; i < KNN; ++i) mx = fmaxf(mx, s_dist[i]);
        float sum = 0.f, e0 = 0.f;
        for (int i = 0; i < KNN; ++i) {
            float e = expf(s_dist[i] - mx);
            sum += e;
            if (i == 0) e0 = e;
        }
        float w = 1.0f - e0 / sum;
        out[b] = w * sqrtf(fmaxf(d2star, EPSF));
    }
}

extern "C" void kernel_launch(void* const* d_in, const int* in_sizes, int n_in,
                              void* d_out, int out_size, void* d_ws, size_t ws_size,
                              hipStream_t stream) {
    const float* emb  = (const float*)d_in[0];
    const float* bank = (const float*)d_in[1];
    float* out = (float*)d_out;

    char* ws = (char*)d_ws;
    u64*   packed = (u64*)   (ws + 0);        //  50176 B
    float* x2     = (float*) (ws + 65536);    //  25088 B
    float* y2     = (float*) (ws + 131072);   //  65536 B
    uint4* binfo  = (uint4*) (ws + 200704);   //    128 B
    float* dnn    = (float*) (ws + 262144);   // 524288 B

    hipMemsetAsync(packed, 0xFF, (size_t)N_EMB * sizeof(u64), stream);

    {
        int rows = M_BANK + N_EMB;               // 22656
        int blocks = (rows + 7) / 8;             // 2832
        rownorm_kernel<<<blocks, 256, 0, stream>>>(emb, bank, x2, y2);
    }

    dist_min_mfma<<<dim3(N_EMB / 128, M_BANK / 128), 256, 0, stream>>>(
        emb, bank, x2, y2, packed);

    argmax_kernel<<<BATCH, 256, 0, stream>>>(packed, binfo);

    dnn_kernel<<<dim3(M_BANK / 256, BATCH), 256, 0, stream>>>(bank, y2, binfo, dnn);

    final_kernel<<<BATCH, 256, 0, stream>>>(emb, bank, x2, y2, binfo, dnn, out);
}

// Round 3
// 229.233 us; speedup vs baseline: 2.8075x; 1.5177x over previous
//
#include <hip/hip_runtime.h>
#include <cstdint>

#define N_EMB 6272      // B*W*H = 8*28*28
#define DIMD  128
#define M_BANK 16384
#define BATCH 8
#define PPB   784       // patches per batch
#define KNN   9
#define EPSF  1e-12f

typedef unsigned long long u64;
typedef _Float16 f16x8 __attribute__((ext_vector_type(8)));
typedef float    f32x4 __attribute__((ext_vector_type(4)));

static __device__ __forceinline__ u64 umin64(u64 a, u64 b) { return b < a ? b : a; }
static __device__ __forceinline__ u64 umax64(u64 a, u64 b) { return b > a ? b : a; }

// async global->LDS, 16B per lane, linear LDS dest (wave-uniform base + lane*16)
static __device__ __forceinline__ void gll16(const _Float16* g, _Float16* l) {
    __builtin_amdgcn_global_load_lds(
        (__attribute__((address_space(1))) void*)(const void*)g,
        (__attribute__((address_space(3))) void*)l, 16, 0, 0);
}

// ---------------- Phase A: convert f32 -> hi/lo fp16 (pre-swizzled) + norms --
// 16 lanes per row; row = gid/16, chunk = gid%16 (8 elems).
// Pre-swizzle within each 32-col quarter q: out chunk jj' = jj ^ ((row>>1)&3).
__global__ __launch_bounds__(256) void convert_kernel(
        const float* __restrict__ emb, const float* __restrict__ bank,
        _Float16* __restrict__ GAh, _Float16* __restrict__ GAl,
        _Float16* __restrict__ GBh, _Float16* __restrict__ GBl,
        float* __restrict__ x2, float* __restrict__ y2) {
    const int gid = blockIdx.x * 256 + threadIdx.x;
    const int row = gid >> 4;
    const int chunk = gid & 15;
    const float* src;
    _Float16 *dh, *dl;
    float* nrm;
    int R;
    if (row < M_BANK) {
        src = bank + (size_t)row * DIMD; dh = GBh; dl = GBl; nrm = y2; R = row;
    } else {
        R = row - M_BANK;
        src = emb + (size_t)R * DIMD; dh = GAh; dl = GAl; nrm = x2;
    }
    float4 v0 = ((const float4*)src)[chunk * 2];
    float4 v1 = ((const float4*)src)[chunk * 2 + 1];
    float f[8] = {v0.x, v0.y, v0.z, v0.w, v1.x, v1.y, v1.z, v1.w};
    f16x8 h, l;
    float s = 0.f;
    #pragma unroll
    for (int e = 0; e < 8; ++e) {
        _Float16 hh = (_Float16)f[e];
        h[e] = hh;
        l[e] = (_Float16)(f[e] - (float)hh);
        s += f[e] * f[e];
    }
    const int q = chunk >> 2, jj = chunk & 3;
    const int jj2 = jj ^ ((R >> 1) & 3);
    const size_t o = (size_t)R * DIMD + q * 32 + jj2 * 8;
    *(f16x8*)(dh + o) = h;
    *(f16x8*)(dl + o) = l;
    #pragma unroll
    for (int off = 1; off < 16; off <<= 1) s += __shfl_xor(s, off, 16);
    if (chunk == 0) nrm[R] = s;
}

// ---------------- Phase B: MFMA dist^2 + per-row min/argmin ----------------
// 128x128 tile, 4 waves (64x64 quadrants), BK=32, 4 phases, double-buffered.
static __device__ __forceinline__ void stage_phase(
        const _Float16* __restrict__ GAh, const _Float16* __restrict__ GAl,
        const _Float16* __restrict__ GBh, const _Float16* __restrict__ GBl,
        _Float16* base, int n0, int m0, int t, int srow, int se8) {
    #pragma unroll
    for (int j = 0; j < 2; ++j) {
        const int row = srow + j * 64;
        const int lo  = row * 32 + se8;
        const size_t ga = (size_t)(n0 + row) * DIMD + t * 32 + se8;
        const size_t gb = (size_t)(m0 + row) * DIMD + t * 32 + se8;
        gll16(GAh + ga, base + lo);
        gll16(GAl + ga, base + 4096 + lo);
        gll16(GBh + gb, base + 8192 + lo);
        gll16(GBl + gb, base + 12288 + lo);
    }
}

static __device__ __forceinline__ void compute_phase(
        const _Float16* base, f32x4 acc[4][4], int wn, int wm, int g, int r16) {
    f16x8 ah[4], al[4], bh[4], bl[4];
    #pragma unroll
    for (int f = 0; f < 4; ++f) {
        const int ra = wn * 64 + f * 16 + r16;
        const int oa = ra * 32 + ((g ^ ((ra >> 1) & 3)) << 3);
        ah[f] = *(const f16x8*)(base + oa);
        al[f] = *(const f16x8*)(base + 4096 + oa);
        const int rb = wm * 64 + f * 16 + r16;
        const int ob = rb * 32 + ((g ^ ((rb >> 1) & 3)) << 3);
        bh[f] = *(const f16x8*)(base + 8192 + ob);
        bl[f] = *(const f16x8*)(base + 12288 + ob);
    }
    #pragma unroll
    for (int i = 0; i < 4; ++i)
        #pragma unroll
        for (int j = 0; j < 4; ++j) {
            acc[i][j] = __builtin_amdgcn_mfma_f32_16x16x32_f16(ah[i], bh[j], acc[i][j], 0, 0, 0);
            acc[i][j] = __builtin_amdgcn_mfma_f32_16x16x32_f16(ah[i], bl[j], acc[i][j], 0, 0, 0);
            acc[i][j] = __builtin_amdgcn_mfma_f32_16x16x32_f16(al[i], bh[j], acc[i][j], 0, 0, 0);
        }
}

__global__ __launch_bounds__(256) void dist_min_mfma(
        const _Float16* __restrict__ GAh, const _Float16* __restrict__ GAl,
        const _Float16* __restrict__ GBh, const _Float16* __restrict__ GBl,
        const float* __restrict__ x2, const float* __restrict__ y2,
        u64* __restrict__ packed) {
    __shared__ _Float16 smem[2 * 4 * 4096];   // 64 KiB: 2 bufs x {Ah,Al,Bh,Bl}[128][32]

    // bijective XCD swizzle: 6272 = 8 * 784
    const int bid = blockIdx.x;
    const int sw  = (bid & 7) * 784 + (bid >> 3);
    const int bx = sw % 49, by = sw / 49;
    const int n0 = bx * 128, m0 = by * 128;

    const int tid  = threadIdx.x;
    const int lane = tid & 63;
    const int wid  = tid >> 6;
    const int wn = wid >> 1, wm = wid & 1;
    const int g   = lane >> 4;     // k-chunk 0..3
    const int r16 = lane & 15;

    const int srow = tid >> 2;         // 0..63
    const int se8  = (tid & 3) * 8;    // elem offset within quarter

    f32x4 acc[4][4] = {};

    stage_phase(GAh, GAl, GBh, GBl, smem, n0, m0, 0, srow, se8);
    __syncthreads();
    #pragma unroll
    for (int t = 0; t < 4; ++t) {
        if (t < 3)
            stage_phase(GAh, GAl, GBh, GBl, smem + ((t + 1) & 1) * 16384,
                        n0, m0, t + 1, srow, se8);
        compute_phase(smem + (t & 1) * 16384, acc, wn, wm, g, r16);
        if (t < 3) __syncthreads();
    }

    // epilogue: d2 = x2 + y2 - 2*dot, pack, 16-lane reduce, atomicMin
    float ys[4];
    #pragma unroll
    for (int j = 0; j < 4; ++j)
        ys[j] = y2[m0 + wm * 64 + j * 16 + r16];

    #pragma unroll
    for (int fi = 0; fi < 4; ++fi) {
        #pragma unroll
        for (int r = 0; r < 4; ++r) {
            const int n = n0 + wn * 64 + fi * 16 + g * 4 + r;
            const float xs = x2[n];
            u64 best = ~0ull;
            #pragma unroll
            for (int fj = 0; fj < 4; ++fj) {
                const int m = m0 + wm * 64 + fj * 16 + r16;
                float d2 = xs + ys[fj] - 2.0f * acc[fi][fj][r];
                d2 = fmaxf(d2, EPSF);
                u64 key = ((u64)__float_as_uint(d2) << 32) | (unsigned)m;
                best = umin64(best, key);
            }
            #pragma unroll
            for (int off = 1; off < 16; off <<= 1)
                best = umin64(best, (u64)__shfl_xor((unsigned long long)best, off));
            if (r16 == 0) atomicMin(&packed[n], best);
        }
    }
}

// ---------------- Phase C1: per-batch argmax of patch score ----------------
__global__ void argmax_kernel(const u64* __restrict__ packed,
                              uint4* __restrict__ binfo) {
    const int b = blockIdx.x, tid = threadIdx.x;
    __shared__ u64 red[256];
    u64 bk = 0;
    for (int p = tid; p < PPB; p += 256) {
        u64 pk = packed[(size_t)b * PPB + p];
        unsigned d2b = (unsigned)(pk >> 32);
        u64 key = ((u64)d2b << 32) | (u64)(0xFFFFFFFFu - (unsigned)p);
        bk = umax64(bk, key);
    }
    red[tid] = bk; __syncthreads();
    for (int s = 128; s; s >>= 1) {
        if (tid < s) red[tid] = umax64(red[tid], red[tid + s]);
        __syncthreads();
    }
    if (tid == 0) {
        u64 w = red[0];
        unsigned p   = 0xFFFFFFFFu - (unsigned)w;
        unsigned d2b = (unsigned)(w >> 32);
        unsigned nn  = (unsigned)packed[(size_t)b * PPB + p];
        binfo[b] = make_uint4(p, nn, d2b, 0u);
    }
}

// ---------------- Phase C2: dist^2(nn_sample, bank) (exact fp32) ----------
__global__ void dnn_kernel(const float* __restrict__ bank,
                           const float* __restrict__ y2,
                           const uint4* __restrict__ binfo,
                           float* __restrict__ dnn) {
    const int b = blockIdx.y;
    const unsigned nn = binfo[b].y;
    __shared__ float nv[DIMD];
    if (threadIdx.x < DIMD) nv[threadIdx.x] = bank[(size_t)nn * DIMD + threadIdx.x];
    __syncthreads();
    const int m = blockIdx.x * 256 + threadIdx.x;
    const float4* row = (const float4*)(bank + (size_t)m * DIMD);
    float dot = 0.f;
    #pragma unroll
    for (int q = 0; q < DIMD / 4; ++q) {
        float4 v = row[q];
        dot += v.x * nv[q*4+0] + v.y * nv[q*4+1] + v.z * nv[q*4+2] + v.w * nv[q*4+3];
    }
    float d2 = y2[nn] + y2[m] - 2.0f * dot;
    dnn[(size_t)b * M_BANK + m] = fmaxf(d2, EPSF);
}

// ---------------- Phase C3: top-9 (reg lists + merge), softmax, output -----
__global__ __launch_bounds__(256) void final_kernel(
        const float* __restrict__ emb,
        const float* __restrict__ bank,
        const float* __restrict__ x2,
        const float* __restrict__ y2,
        const uint4* __restrict__ binfo,
        const float* __restrict__ dnn,
        float* __restrict__ out) {
    const int b = blockIdx.x, tid = threadIdx.x;
    __shared__ u64 lists[256 * KNN];   // 18 KiB
    __shared__ u64 red4[4];
    __shared__ u64 s_wkey;
    __shared__ unsigned s_sel[KNN];
    __shared__ float s_dist[KNN];
    __shared__ float xv[DIMD];

    const uint4 info = binfo[b];
    const unsigned nstar = info.x;
    const float d2star = __uint_as_float(info.z);
    if (tid < DIMD) xv[tid] = emb[(size_t)(b * PPB + nstar) * DIMD + tid];

    // per-thread sorted top-9 over 64 strided values (all-static indexing)
    u64 lst[KNN];
    #pragma unroll
    for (int s = 0; s < KNN; ++s) lst[s] = ~0ull;
    for (int i = 0; i < M_BANK / 256; ++i) {
        const int m = tid + (i << 8);
        const float v = dnn[(size_t)b * M_BANK + m];
        const u64 key = ((u64)__float_as_uint(v) << 32) | (unsigned)m;
        if (key < lst[KNN - 1]) {
            lst[KNN - 1] = key;
            #pragma unroll
            for (int s = KNN - 1; s > 0; --s) {
                u64 a = lst[s - 1], c = lst[s];
                lst[s - 1] = umin64(a, c);
                lst[s]     = umax64(a, c);
            }
        }
    }
    #pragma unroll
    for (int s = 0; s < KNN; ++s) lists[tid * KNN + s] = lst[s];
    __syncthreads();

    // 9-round merge of 256 sorted lists
    int p = 0;
    for (int r = 0; r < KNN; ++r) {
        u64 h = (p < KNN) ? lists[tid * KNN + p] : ~0ull;
        #pragma unroll
        for (int off = 1; off < 64; off <<= 1)
            h = umin64(h, (u64)__shfl_xor((unsigned long long)h, off));
        if ((tid & 63) == 0) red4[tid >> 6] = h;
        __syncthreads();
        if (tid == 0) {
            u64 w = umin64(umin64(red4[0], red4[1]), umin64(red4[2], red4[3]));
            s_wkey = w;
            s_sel[r] = (unsigned)w;
        }
        __syncthreads();
        const u64 w = s_wkey;
        if (p < KNN && lists[tid * KNN + p] == w) ++p;
    }

    if (tid < KNN) {
        const unsigned s = s_sel[tid];
        const float* srow = bank + (size_t)s * DIMD;
        float dot = 0.f;
        for (int d = 0; d < DIMD; ++d) dot += srow[d] * xv[d];
        float d2 = x2[b * PPB + nstar] + y2[s] - 2.0f * dot;
        s_dist[tid] = sqrtf(fmaxf(d2, EPSF));
    }
    __syncthreads();

    if (tid == 0) {
        float mx = s_dist[0];
        for (int i = 1; i < KNN; ++i) mx = fmaxf(mx, s_dist[i]);
        float sum = 0.f, e0 = 0.f;
        for (int i = 0; i < KNN; ++i) {
            float e = expf(s_dist[i] - mx);
            sum += e;
            if (i == 0) e0 = e;
        }
        float w = 1.0f - e0 / sum;
        out[b] = w * sqrtf(fmaxf(d2star, EPSF));
    }
}

extern "C" void kernel_launch(void* const* d_in, const int* in_sizes, int n_in,
                              void* d_out, int out_size, void* d_ws, size_t ws_size,
                              hipStream_t stream) {
    const float* emb  = (const float*)d_in[0];
    const float* bank = (const float*)d_in[1];
    float* out = (float*)d_out;

    char* ws = (char*)d_ws;
    u64*      packed = (u64*)      (ws + 0);         //  50176 B
    float*    x2     = (float*)    (ws + 65536);     //  25088 B
    float*    y2     = (float*)    (ws + 131072);    //  65536 B
    uint4*    binfo  = (uint4*)    (ws + 200704);    //    128 B
    float*    dnn    = (float*)    (ws + 262144);    // 524288 B
    _Float16* GAh    = (_Float16*) (ws + 786432);    // 1605632 B
    _Float16* GAl    = (_Float16*) (ws + 2392064);   // 1605632 B
    _Float16* GBh    = (_Float16*) (ws + 3997696);   // 4194304 B
    _Float16* GBl    = (_Float16*) (ws + 8192000);   // 4194304 B  (end 12386304)

    hipMemsetAsync(packed, 0xFF, (size_t)N_EMB * sizeof(u64), stream);

    {
        const int rows = M_BANK + N_EMB;             // 22656
        const int blocks = rows * 16 / 256;          // 1416
        convert_kernel<<<blocks, 256, 0, stream>>>(emb, bank, GAh, GAl, GBh, GBl, x2, y2);
    }

    dist_min_mfma<<<N_EMB / 128 * (M_BANK / 128), 256, 0, stream>>>(
        GAh, GAl, GBh, GBl, x2, y2, packed);

    argmax_kernel<<<BATCH, 256, 0, stream>>>(packed, binfo);

    dnn_kernel<<<dim3(M_BANK / 256, BATCH), 256, 0, stream>>>(bank, y2, binfo, dnn);

    final_kernel<<<BATCH, 256, 0, stream>>>(emb, bank, x2, y2, binfo, dnn, out);
}

// Round 4
// 150.625 us; speedup vs baseline: 4.2727x; 1.5219x over previous
//
#include <hip/hip_runtime.h>
#include <cstdint>

#define N_EMB 6272      // B*W*H = 8*28*28
#define DIMD  128
#define M_BANK 16384
#define BATCH 8
#define PPB   784       // patches per batch
#define KNN   9
#define EPSF  1e-12f

typedef unsigned long long u64;
typedef _Float16 f16x8 __attribute__((ext_vector_type(8)));
typedef float    f32x4 __attribute__((ext_vector_type(4)));

static __device__ __forceinline__ u64 umin64(u64 a, u64 b) { return b < a ? b : a; }
static __device__ __forceinline__ u64 umax64(u64 a, u64 b) { return b > a ? b : a; }

// async global->LDS, 16B per lane, linear LDS dest (wave-uniform base + lane*16)
static __device__ __forceinline__ void gll16(const _Float16* g, _Float16* l) {
    __builtin_amdgcn_global_load_lds(
        (__attribute__((address_space(1))) void*)(const void*)g,
        (__attribute__((address_space(3))) void*)l, 16, 0, 0);
}

// ---------------- Phase A: convert f32 -> fp16 (pre-swizzled) + exact norms --
// 16 lanes per row; row = gid/16, chunk = gid%16 (8 elems).
// Pre-swizzle within each 32-col quarter q: out chunk jj' = jj ^ ((row>>1)&3).
__global__ __launch_bounds__(256) void convert_kernel(
        const float* __restrict__ emb, const float* __restrict__ bank,
        _Float16* __restrict__ GAh, _Float16* __restrict__ GBh,
        float* __restrict__ x2, float* __restrict__ y2) {
    const int gid = blockIdx.x * 256 + threadIdx.x;
    const int row = gid >> 4;
    const int chunk = gid & 15;
    const float* src;
    _Float16* dh;
    float* nrm;
    int R;
    if (row < M_BANK) {
        src = bank + (size_t)row * DIMD; dh = GBh; nrm = y2; R = row;
    } else {
        R = row - M_BANK;
        src = emb + (size_t)R * DIMD; dh = GAh; nrm = x2;
    }
    float4 v0 = ((const float4*)src)[chunk * 2];
    float4 v1 = ((const float4*)src)[chunk * 2 + 1];
    float f[8] = {v0.x, v0.y, v0.z, v0.w, v1.x, v1.y, v1.z, v1.w};
    f16x8 h;
    float s = 0.f;
    #pragma unroll
    for (int e = 0; e < 8; ++e) {
        h[e] = (_Float16)f[e];
        s += f[e] * f[e];
    }
    const int q = chunk >> 2, jj = chunk & 3;
    const int jj2 = jj ^ ((R >> 1) & 3);
    *(f16x8*)(dh + (size_t)R * DIMD + q * 32 + jj2 * 8) = h;
    #pragma unroll
    for (int off = 1; off < 16; off <<= 1) s += __shfl_xor(s, off, 16);
    if (chunk == 0) nrm[R] = s;
}

// ---------------- Phase B: MFMA approx dist^2 + per-row min/argmin ----------
// 128x128 tile, 4 waves (64x64 quadrants), BK=32, 4 phases, double-buffered.
// fp16 hi-only: d2 error ~1e-2 absolute vs O(1) neighbor gaps -> selection-safe;
// selected pair is exactly rescored in argmax_kernel.
static __device__ __forceinline__ void stage_phase(
        const _Float16* __restrict__ GAh, const _Float16* __restrict__ GBh,
        _Float16* base, int n0, int m0, int t, int srow, int se8) {
    #pragma unroll
    for (int j = 0; j < 2; ++j) {
        const int row = srow + j * 64;
        const int lo  = row * 32 + se8;
        gll16(GAh + (size_t)(n0 + row) * DIMD + t * 32 + se8, base + lo);
        gll16(GBh + (size_t)(m0 + row) * DIMD + t * 32 + se8, base + 4096 + lo);
    }
}

static __device__ __forceinline__ void compute_phase(
        const _Float16* base, f32x4 acc[4][4], int wn, int wm, int g, int r16) {
    f16x8 ah[4], bh[4];
    #pragma unroll
    for (int f = 0; f < 4; ++f) {
        const int ra = wn * 64 + f * 16 + r16;
        ah[f] = *(const f16x8*)(base + ra * 32 + ((g ^ ((ra >> 1) & 3)) << 3));
        const int rb = wm * 64 + f * 16 + r16;
        bh[f] = *(const f16x8*)(base + 4096 + rb * 32 + ((g ^ ((rb >> 1) & 3)) << 3));
    }
    #pragma unroll
    for (int i = 0; i < 4; ++i)
        #pragma unroll
        for (int j = 0; j < 4; ++j)
            acc[i][j] = __builtin_amdgcn_mfma_f32_16x16x32_f16(ah[i], bh[j], acc[i][j], 0, 0, 0);
}

__global__ __launch_bounds__(256, 4) void dist_min_mfma(
        const _Float16* __restrict__ GAh, const _Float16* __restrict__ GBh,
        const float* __restrict__ x2, const float* __restrict__ y2,
        u64* __restrict__ packed) {
    __shared__ _Float16 smem[2 * 2 * 4096];   // 32 KiB: 2 bufs x {Ah,Bh}[128][32]

    // bijective XCD swizzle: 6272 = 8 * 784
    const int bid = blockIdx.x;
    const int sw  = (bid & 7) * 784 + (bid >> 3);
    const int bx = sw % 49, by = sw / 49;
    const int n0 = bx * 128, m0 = by * 128;

    const int tid  = threadIdx.x;
    const int lane = tid & 63;
    const int wid  = tid >> 6;
    const int wn = wid >> 1, wm = wid & 1;
    const int g   = lane >> 4;     // k-chunk 0..3
    const int r16 = lane & 15;

    const int srow = tid >> 2;         // 0..63
    const int se8  = (tid & 3) * 8;    // elem offset within quarter

    f32x4 acc[4][4] = {};

    stage_phase(GAh, GBh, smem, n0, m0, 0, srow, se8);
    __syncthreads();
    #pragma unroll
    for (int t = 0; t < 4; ++t) {
        if (t < 3)
            stage_phase(GAh, GBh, smem + ((t + 1) & 1) * 8192, n0, m0, t + 1, srow, se8);
        compute_phase(smem + (t & 1) * 8192, acc, wn, wm, g, r16);
        if (t < 3) __syncthreads();
    }

    // epilogue: d2 ~= x2 + y2 - 2*dot, pack, 16-lane reduce, atomicMin
    float ys[4];
    #pragma unroll
    for (int j = 0; j < 4; ++j)
        ys[j] = y2[m0 + wm * 64 + j * 16 + r16];

    #pragma unroll
    for (int fi = 0; fi < 4; ++fi) {
        #pragma unroll
        for (int r = 0; r < 4; ++r) {
            const int n = n0 + wn * 64 + fi * 16 + g * 4 + r;
            const float xs = x2[n];
            u64 best = ~0ull;
            #pragma unroll
            for (int fj = 0; fj < 4; ++fj) {
                const int m = m0 + wm * 64 + fj * 16 + r16;
                float d2 = xs + ys[fj] - 2.0f * acc[fi][fj][r];
                d2 = fmaxf(d2, EPSF);
                u64 key = ((u64)__float_as_uint(d2) << 32) | (unsigned)m;
                best = umin64(best, key);
            }
            #pragma unroll
            for (int off = 1; off < 16; off <<= 1)
                best = umin64(best, (u64)__shfl_xor((unsigned long long)best, off));
            if (r16 == 0) atomicMin(&packed[n], best);
        }
    }
}

// ------- Phase C1: per-batch argmax of patch score + EXACT fp32 rescore -----
__global__ __launch_bounds__(256) void argmax_kernel(
        const u64* __restrict__ packed,
        const float* __restrict__ emb, const float* __restrict__ bank,
        const float* __restrict__ x2, const float* __restrict__ y2,
        uint4* __restrict__ binfo) {
    const int b = blockIdx.x, tid = threadIdx.x;
    __shared__ u64 red[256];
    __shared__ float fred[256];
    __shared__ unsigned s_p, s_nn;
    u64 bk = 0;
    for (int p = tid; p < PPB; p += 256) {
        u64 pk = packed[(size_t)b * PPB + p];
        unsigned d2b = (unsigned)(pk >> 32);
        u64 key = ((u64)d2b << 32) | (u64)(0xFFFFFFFFu - (unsigned)p);
        bk = umax64(bk, key);
    }
    red[tid] = bk; __syncthreads();
    for (int s = 128; s; s >>= 1) {
        if (tid < s) red[tid] = umax64(red[tid], red[tid + s]);
        __syncthreads();
    }
    if (tid == 0) {
        u64 w = red[0];
        unsigned p = 0xFFFFFFFFu - (unsigned)w;
        s_p = p;
        s_nn = (unsigned)packed[(size_t)b * PPB + p];
    }
    __syncthreads();
    // exact fp32 d2 for the selected pair
    const unsigned p = s_p, nn = s_nn;
    float prod = 0.f;
    if (tid < DIMD)
        prod = emb[(size_t)(b * PPB + p) * DIMD + tid] * bank[(size_t)nn * DIMD + tid];
    fred[tid] = prod; __syncthreads();
    for (int s = 128; s; s >>= 1) {
        if (tid < s) fred[tid] += fred[tid + s];
        __syncthreads();
    }
    if (tid == 0) {
        float d2 = x2[b * PPB + p] + y2[nn] - 2.0f * fred[0];
        binfo[b] = make_uint4(p, nn, __float_as_uint(fmaxf(d2, EPSF)), 0u);
    }
}

// ---------------- Phase C2: dist^2(nn_sample, bank) (exact fp32) ----------
__global__ void dnn_kernel(const float* __restrict__ bank,
                           const float* __restrict__ y2,
                           const uint4* __restrict__ binfo,
                           float* __restrict__ dnn) {
    const int b = blockIdx.y;
    const unsigned nn = binfo[b].y;
    __shared__ float nv[DIMD];
    if (threadIdx.x < DIMD) nv[threadIdx.x] = bank[(size_t)nn * DIMD + threadIdx.x];
    __syncthreads();
    const int m = blockIdx.x * 256 + threadIdx.x;
    const float4* row = (const float4*)(bank + (size_t)m * DIMD);
    float dot = 0.f;
    #pragma unroll
    for (int q = 0; q < DIMD / 4; ++q) {
        float4 v = row[q];
        dot += v.x * nv[q*4+0] + v.y * nv[q*4+1] + v.z * nv[q*4+2] + v.w * nv[q*4+3];
    }
    float d2 = y2[nn] + y2[m] - 2.0f * dot;
    dnn[(size_t)b * M_BANK + m] = fmaxf(d2, EPSF);
}

// ---------------- Phase C3: top-9 (reg lists + merge), softmax, output -----
__global__ __launch_bounds__(256) void final_kernel(
        const float* __restrict__ emb,
        const float* __restrict__ bank,
        const float* __restrict__ x2,
        const float* __restrict__ y2,
        const uint4* __restrict__ binfo,
        const float* __restrict__ dnn,
        float* __restrict__ out) {
    const int b = blockIdx.x, tid = threadIdx.x;
    __shared__ u64 lists[256 * KNN];   // 18 KiB
    __shared__ u64 red4[4];
    __shared__ u64 s_wkey;
    __shared__ unsigned s_sel[KNN];
    __shared__ float s_dist[KNN];
    __shared__ float xv[DIMD];

    const uint4 info = binfo[b];
    const unsigned nstar = info.x;
    const float d2star = __uint_as_float(info.z);
    if (tid < DIMD) xv[tid] = emb[(size_t)(b * PPB + nstar) * DIMD + tid];

    // per-thread sorted top-9 over 64 strided values (all-static indexing)
    u64 lst[KNN];
    #pragma unroll
    for (int s = 0; s < KNN; ++s) lst[s] = ~0ull;
    for (int i = 0; i < M_BANK / 256; ++i) {
        const int m = tid + (i << 8);
        const float v = dnn[(size_t)b * M_BANK + m];
        const u64 key = ((u64)__float_as_uint(v) << 32) | (unsigned)m;
        if (key < lst[KNN - 1]) {
            lst[KNN - 1] = key;
            #pragma unroll
            for (int s = KNN - 1; s > 0; --s) {
                u64 a = lst[s - 1], c = lst[s];
                lst[s - 1] = umin64(a, c);
                lst[s]     = umax64(a, c);
            }
        }
    }
    #pragma unroll
    for (int s = 0; s < KNN; ++s) lists[tid * KNN + s] = lst[s];
    __syncthreads();

    // 9-round merge of 256 sorted lists
    int p = 0;
    for (int r = 0; r < KNN; ++r) {
        u64 h = (p < KNN) ? lists[tid * KNN + p] : ~0ull;
        #pragma unroll
        for (int off = 1; off < 64; off <<= 1)
            h = umin64(h, (u64)__shfl_xor((unsigned long long)h, off));
        if ((tid & 63) == 0) red4[tid >> 6] = h;
        __syncthreads();
        if (tid == 0) {
            u64 w = umin64(umin64(red4[0], red4[1]), umin64(red4[2], red4[3]));
            s_wkey = w;
            s_sel[r] = (unsigned)w;
        }
        __syncthreads();
        const u64 w = s_wkey;
        if (p < KNN && lists[tid * KNN + p] == w) ++p;
    }

    if (tid < KNN) {
        const unsigned s = s_sel[tid];
        const float* srow = bank + (size_t)s * DIMD;
        float dot = 0.f;
        for (int d = 0; d < DIMD; ++d) dot += srow[d] * xv[d];
        float d2 = x2[b * PPB + nstar] + y2[s] - 2.0f * dot;
        s_dist[tid] = sqrtf(fmaxf(d2, EPSF));
    }
    __syncthreads();

    if (tid == 0) {
        float mx = s_dist[0];
        for (int i = 1; i < KNN; ++i) mx = fmaxf(mx, s_dist[i]);
        float sum = 0.f, e0 = 0.f;
        for (int i = 0; i < KNN; ++i) {
            float e = expf(s_dist[i] - mx);
            sum += e;
            if (i == 0) e0 = e;
        }
        float w = 1.0f - e0 / sum;
        out[b] = w * sqrtf(fmaxf(d2star, EPSF));
    }
}

extern "C" void kernel_launch(void* const* d_in, const int* in_sizes, int n_in,
                              void* d_out, int out_size, void* d_ws, size_t ws_size,
                              hipStream_t stream) {
    const float* emb  = (const float*)d_in[0];
    const float* bank = (const float*)d_in[1];
    float* out = (float*)d_out;

    char* ws = (char*)d_ws;
    u64*      packed = (u64*)      (ws + 0);         //  50176 B
    float*    x2     = (float*)    (ws + 65536);     //  25088 B
    float*    y2     = (float*)    (ws + 131072);    //  65536 B
    uint4*    binfo  = (uint4*)    (ws + 200704);    //    128 B
    float*    dnn    = (float*)    (ws + 262144);    // 524288 B
    _Float16* GAh    = (_Float16*) (ws + 786432);    // 1605632 B
    _Float16* GBh    = (_Float16*) (ws + 2392064);   // 4194304 B  (end 6586368)

    hipMemsetAsync(packed, 0xFF, (size_t)N_EMB * sizeof(u64), stream);

    {
        const int rows = M_BANK + N_EMB;             // 22656
        const int blocks = rows * 16 / 256;          // 1416
        convert_kernel<<<blocks, 256, 0, stream>>>(emb, bank, GAh, GBh, x2, y2);
    }

    dist_min_mfma<<<N_EMB / 128 * (M_BANK / 128), 256, 0, stream>>>(
        GAh, GBh, x2, y2, packed);

    argmax_kernel<<<BATCH, 256, 0, stream>>>(packed, emb, bank, x2, y2, binfo);

    dnn_kernel<<<dim3(M_BANK / 256, BATCH), 256, 0, stream>>>(bank, y2, binfo, dnn);

    final_kernel<<<BATCH, 256, 0, stream>>>(emb, bank, x2, y2, binfo, dnn, out);
}

// Round 5
// 109.190 us; speedup vs baseline: 5.8940x; 1.3795x over previous
//
#include <hip/hip_runtime.h>
#include <cstdint>

#define N_EMB 6272      // B*W*H = 8*28*28
#define DIMD  128
#define M_BANK 16384
#define BATCH 8
#define PPB   784       // patches per batch
#define KNN   9
#define EPSF  1e-12f

typedef unsigned long long u64;
typedef _Float16 f16x8 __attribute__((ext_vector_type(8)));
typedef float    f32x4 __attribute__((ext_vector_type(4)));

static __device__ __forceinline__ u64 umin64(u64 a, u64 b) { return b < a ? b : a; }
static __device__ __forceinline__ u64 umax64(u64 a, u64 b) { return b > a ? b : a; }

// async global->LDS, 16B per lane, linear LDS dest (wave-uniform base + lane*16)
static __device__ __forceinline__ void gll16(const _Float16* g, _Float16* l) {
    __builtin_amdgcn_global_load_lds(
        (__attribute__((address_space(1))) void*)(const void*)g,
        (__attribute__((address_space(3))) void*)l, 16, 0, 0);
}

// ---------------- Phase A: convert f32 -> fp16 (pre-swizzled) + exact norms --
// Also initializes packed[] (replaces the separate memset dispatch).
// 16 lanes per row; row = gid/16, chunk = gid%16 (8 elems).
// Pre-swizzle within each 32-col quarter q: out chunk jj' = jj ^ ((row>>1)&3).
__global__ __launch_bounds__(256) void convert_kernel(
        const float* __restrict__ emb, const float* __restrict__ bank,
        _Float16* __restrict__ GAh, _Float16* __restrict__ GBh,
        float* __restrict__ x2, float* __restrict__ y2,
        u64* __restrict__ packed) {
    const int gid = blockIdx.x * 256 + threadIdx.x;
    if (gid < N_EMB) packed[gid] = ~0ull;
    const int row = gid >> 4;
    const int chunk = gid & 15;
    const float* src;
    _Float16* dh;
    float* nrm;
    int R;
    if (row < M_BANK) {
        src = bank + (size_t)row * DIMD; dh = GBh; nrm = y2; R = row;
    } else {
        R = row - M_BANK;
        src = emb + (size_t)R * DIMD; dh = GAh; nrm = x2;
    }
    float4 v0 = ((const float4*)src)[chunk * 2];
    float4 v1 = ((const float4*)src)[chunk * 2 + 1];
    float f[8] = {v0.x, v0.y, v0.z, v0.w, v1.x, v1.y, v1.z, v1.w};
    f16x8 h;
    float s = 0.f;
    #pragma unroll
    for (int e = 0; e < 8; ++e) {
        h[e] = (_Float16)f[e];
        s += f[e] * f[e];
    }
    const int q = chunk >> 2, jj = chunk & 3;
    const int jj2 = jj ^ ((R >> 1) & 3);
    *(f16x8*)(dh + (size_t)R * DIMD + q * 32 + jj2 * 8) = h;
    #pragma unroll
    for (int off = 1; off < 16; off <<= 1) s += __shfl_xor(s, off, 16);
    if (chunk == 0) nrm[R] = s;
}

// ---------------- Phase B: MFMA approx dist^2 + per-row min/argmin ----------
// A-in-registers persistent-m design:
//   grid = 49 n-tiles x 16 m-chunks = 784 blocks, 4 waves (2x2 64x64 quadrants)
//   per block: A (128 x K128) loaded to regs ONCE (16 f16x8/wave),
//   loop 8 m-tiles: B (128 x 64k) double-buffered in LDS, BK=64, 2 phases/tile.
// LDS = A-stage 32KB + 2x16KB B = 64KB -> 2 blocks/CU.

// stage 128 rows x 64 cols (one k-half, 16 KB): 4 gll16/thread
static __device__ __forceinline__ void stageB(
        const _Float16* __restrict__ GBh, _Float16* dst,
        int mrow0, int h, int srow, int se8) {
    #pragma unroll
    for (int j = 0; j < 2; ++j) {
        const int row = srow + j * 64;
        #pragma unroll
        for (int q = 0; q < 2; ++q)
            gll16(GBh + (size_t)(mrow0 + row) * DIMD + h * 64 + q * 32 + se8,
                  dst + q * 4096 + row * 32 + se8);
    }
}

template<int H>
static __device__ __forceinline__ void computeB(
        const _Float16* bb, const f16x8 (&a)[4][4], f32x4 (&acc)[4][4],
        int wm, int g, int r16) {
    f16x8 b[4][2];
    #pragma unroll
    for (int fj = 0; fj < 4; ++fj) {
        const int row = wm * 64 + fj * 16 + r16;
        const int sw = (g ^ ((row >> 1) & 3)) << 3;
        b[fj][0] = *(const f16x8*)&bb[row * 32 + sw];
        b[fj][1] = *(const f16x8*)&bb[4096 + row * 32 + sw];
    }
    #pragma unroll
    for (int ks = 0; ks < 2; ++ks)
        #pragma unroll
        for (int fi = 0; fi < 4; ++fi)
            #pragma unroll
            for (int fj = 0; fj < 4; ++fj)
                acc[fi][fj] = __builtin_amdgcn_mfma_f32_16x16x32_f16(
                    a[fi][2 * H + ks], b[fj][ks], acc[fi][fj], 0, 0, 0);
}

__global__ __launch_bounds__(256, 2) void dist_min_mfma(
        const _Float16* __restrict__ GAh, const _Float16* __restrict__ GBh,
        const float* __restrict__ x2, const float* __restrict__ y2,
        u64* __restrict__ packed) {
    __shared__ _Float16 smem[32768];   // 64 KiB: A[4][128][32] | B0 | B1

    const int bid = blockIdx.x;
    const int c   = bid & 15;          // m-chunk; all its blocks on XCD c&7
    const int nt  = bid >> 4;          // 0..48
    const int n0  = nt * 128;
    const int mbase = c * 1024;

    const int tid  = threadIdx.x;
    const int lane = tid & 63;
    const int wid  = tid >> 6;
    const int wn = wid >> 1, wm = wid & 1;
    const int g = lane >> 4, r16 = lane & 15;
    const int srow = tid >> 2;
    const int se8  = (tid & 3) * 8;

    _Float16* sB0 = smem + 16384;
    _Float16* sB1 = smem + 24576;

    // ---- prologue: stage A (32 KB) + B(t=0, h=0) ----
    #pragma unroll
    for (int k = 0; k < 4; ++k)
        #pragma unroll
        for (int j = 0; j < 2; ++j) {
            const int row = srow + j * 64;
            gll16(GAh + (size_t)(n0 + row) * DIMD + k * 32 + se8,
                  smem + k * 4096 + row * 32 + se8);
        }
    stageB(GBh, sB0, mbase, 0, srow, se8);

    float xs[4][4];
    #pragma unroll
    for (int fi = 0; fi < 4; ++fi)
        #pragma unroll
        for (int r = 0; r < 4; ++r)
            xs[fi][r] = x2[n0 + wn * 64 + fi * 16 + g * 4 + r];

    __syncthreads();

    // A fragments -> registers (held for the whole kernel)
    f16x8 a[4][4];
    #pragma unroll
    for (int fi = 0; fi < 4; ++fi) {
        const int row = wn * 64 + fi * 16 + r16;
        const int sw = (g ^ ((row >> 1) & 3)) << 3;
        #pragma unroll
        for (int k = 0; k < 4; ++k)
            a[fi][k] = *(const f16x8*)&smem[k * 4096 + row * 32 + sw];
    }

    f32x4 acc[4][4];
    #pragma unroll
    for (int fi = 0; fi < 4; ++fi)
        #pragma unroll
        for (int fj = 0; fj < 4; ++fj)
            acc[fi][fj] = (f32x4){0.f, 0.f, 0.f, 0.f};

    float runmin[4][4];
    int   runidx[4][4];
    #pragma unroll
    for (int fi = 0; fi < 4; ++fi)
        #pragma unroll
        for (int r = 0; r < 4; ++r) { runmin[fi][r] = 3.4e38f; runidx[fi][r] = 0; }

    for (int t = 0; t < 8; ++t) {
        const int mt = mbase + t * 128;
        stageB(GBh, sB1, mt, 1, srow, se8);           // k-half 1 of tile t
        computeB<0>(sB0, a, acc, wm, g, r16);
        __syncthreads();
        if (t < 7) stageB(GBh, sB0, mt + 128, 0, srow, se8);  // k-half 0 of t+1
        float ys[4];
        #pragma unroll
        for (int fj = 0; fj < 4; ++fj)
            ys[fj] = y2[mt + wm * 64 + fj * 16 + r16];
        computeB<1>(sB1, a, acc, wm, g, r16);

        // fold tile t into runmin/runidx, reset acc (covers stage latency)
        const int mwave = mt + wm * 64 + r16;
        #pragma unroll
        for (int fi = 0; fi < 4; ++fi) {
            #pragma unroll
            for (int r = 0; r < 4; ++r) {
                float d0 = fmaxf(fmaf(-2.f, acc[fi][0][r], xs[fi][r] + ys[0]), EPSF);
                float d1 = fmaxf(fmaf(-2.f, acc[fi][1][r], xs[fi][r] + ys[1]), EPSF);
                float d2v = fmaxf(fmaf(-2.f, acc[fi][2][r], xs[fi][r] + ys[2]), EPSF);
                float d3 = fmaxf(fmaf(-2.f, acc[fi][3][r], xs[fi][r] + ys[3]), EPSF);
                float m01 = fminf(d0, d1);  int i01 = d1 < d0 ? 1 : 0;
                float m23 = fminf(d2v, d3); int i23 = d3 < d2v ? 3 : 2;
                float tm  = fminf(m01, m23); int ti = m23 < m01 ? i23 : i01;
                if (tm < runmin[fi][r]) {
                    runmin[fi][r] = tm;
                    runidx[fi][r] = mwave + ti * 16;
                }
            }
            #pragma unroll
            for (int fj = 0; fj < 4; ++fj)
                acc[fi][fj] = (f32x4){0.f, 0.f, 0.f, 0.f};
        }
        __syncthreads();
    }

    // ---- final: pack, 16-lane reduce, atomicMin ----
    #pragma unroll
    for (int fi = 0; fi < 4; ++fi) {
        #pragma unroll
        for (int r = 0; r < 4; ++r) {
            const int n = n0 + wn * 64 + fi * 16 + g * 4 + r;
            u64 best = ((u64)__float_as_uint(runmin[fi][r]) << 32)
                     | (unsigned)runidx[fi][r];
            #pragma unroll
            for (int off = 1; off < 16; off <<= 1)
                best = umin64(best, (u64)__shfl_xor((unsigned long long)best, off));
            if (r16 == 0) atomicMin(&packed[n], best);
        }
    }
}

// ------- Phase C1: per-batch argmax of patch score + EXACT fp32 rescore -----
__global__ __launch_bounds__(256) void argmax_kernel(
        const u64* __restrict__ packed,
        const float* __restrict__ emb, const float* __restrict__ bank,
        const float* __restrict__ x2, const float* __restrict__ y2,
        uint4* __restrict__ binfo) {
    const int b = blockIdx.x, tid = threadIdx.x;
    __shared__ u64 red[256];
    __shared__ float fred[256];
    __shared__ unsigned s_p, s_nn;
    u64 bk = 0;
    for (int p = tid; p < PPB; p += 256) {
        u64 pk = packed[(size_t)b * PPB + p];
        unsigned d2b = (unsigned)(pk >> 32);
        u64 key = ((u64)d2b << 32) | (u64)(0xFFFFFFFFu - (unsigned)p);
        bk = umax64(bk, key);
    }
    red[tid] = bk; __syncthreads();
    for (int s = 128; s; s >>= 1) {
        if (tid < s) red[tid] = umax64(red[tid], red[tid + s]);
        __syncthreads();
    }
    if (tid == 0) {
        u64 w = red[0];
        unsigned p = 0xFFFFFFFFu - (unsigned)w;
        s_p = p;
        s_nn = (unsigned)packed[(size_t)b * PPB + p];
    }
    __syncthreads();
    const unsigned p = s_p, nn = s_nn;
    float prod = 0.f;
    if (tid < DIMD)
        prod = emb[(size_t)(b * PPB + p) * DIMD + tid] * bank[(size_t)nn * DIMD + tid];
    fred[tid] = prod; __syncthreads();
    for (int s = 128; s; s >>= 1) {
        if (tid < s) fred[tid] += fred[tid + s];
        __syncthreads();
    }
    if (tid == 0) {
        float d2 = x2[b * PPB + p] + y2[nn] - 2.0f * fred[0];
        binfo[b] = make_uint4(p, nn, __float_as_uint(fmaxf(d2, EPSF)), 0u);
    }
}

// ---------------- Phase C2: dist^2(nn_sample, bank) (exact fp32) ----------
__global__ void dnn_kernel(const float* __restrict__ bank,
                           const float* __restrict__ y2,
                           const uint4* __restrict__ binfo,
                           float* __restrict__ dnn) {
    const int b = blockIdx.y;
    const unsigned nn = binfo[b].y;
    __shared__ float nv[DIMD];
    if (threadIdx.x < DIMD) nv[threadIdx.x] = bank[(size_t)nn * DIMD + threadIdx.x];
    __syncthreads();
    const int m = blockIdx.x * 256 + threadIdx.x;
    const float4* row = (const float4*)(bank + (size_t)m * DIMD);
    float dot = 0.f;
    #pragma unroll
    for (int q = 0; q < DIMD / 4; ++q) {
        float4 v = row[q];
        dot += v.x * nv[q*4+0] + v.y * nv[q*4+1] + v.z * nv[q*4+2] + v.w * nv[q*4+3];
    }
    float d2 = y2[nn] + y2[m] - 2.0f * dot;
    dnn[(size_t)b * M_BANK + m] = fmaxf(d2, EPSF);
}

// ---------------- Phase C3: top-9 (reg lists + merge), softmax, output -----
__global__ __launch_bounds__(256) void final_kernel(
        const float* __restrict__ emb,
        const float* __restrict__ bank,
        const float* __restrict__ x2,
        const float* __restrict__ y2,
        const uint4* __restrict__ binfo,
        const float* __restrict__ dnn,
        float* __restrict__ out) {
    const int b = blockIdx.x, tid = threadIdx.x;
    __shared__ u64 lists[256 * KNN];   // 18 KiB
    __shared__ u64 red4[4];
    __shared__ u64 s_wkey;
    __shared__ unsigned s_sel[KNN];
    __shared__ float s_dist[KNN];
    __shared__ float xv[DIMD];

    const uint4 info = binfo[b];
    const unsigned nstar = info.x;
    const float d2star = __uint_as_float(info.z);
    if (tid < DIMD) xv[tid] = emb[(size_t)(b * PPB + nstar) * DIMD + tid];

    u64 lst[KNN];
    #pragma unroll
    for (int s = 0; s < KNN; ++s) lst[s] = ~0ull;
    for (int i = 0; i < M_BANK / 256; ++i) {
        const int m = tid + (i << 8);
        const float v = dnn[(size_t)b * M_BANK + m];
        const u64 key = ((u64)__float_as_uint(v) << 32) | (unsigned)m;
        if (key < lst[KNN - 1]) {
            lst[KNN - 1] = key;
            #pragma unroll
            for (int s = KNN - 1; s > 0; --s) {
                u64 a = lst[s - 1], cc = lst[s];
                lst[s - 1] = umin64(a, cc);
                lst[s]     = umax64(a, cc);
            }
        }
    }
    #pragma unroll
    for (int s = 0; s < KNN; ++s) lists[tid * KNN + s] = lst[s];
    __syncthreads();

    int p = 0;
    for (int r = 0; r < KNN; ++r) {
        u64 h = (p < KNN) ? lists[tid * KNN + p] : ~0ull;
        #pragma unroll
        for (int off = 1; off < 64; off <<= 1)
            h = umin64(h, (u64)__shfl_xor((unsigned long long)h, off));
        if ((tid & 63) == 0) red4[tid >> 6] = h;
        __syncthreads();
        if (tid == 0) {
            u64 w = umin64(umin64(red4[0], red4[1]), umin64(red4[2], red4[3]));
            s_wkey = w;
            s_sel[r] = (unsigned)w;
        }
        __syncthreads();
        const u64 w = s_wkey;
        if (p < KNN && lists[tid * KNN + p] == w) ++p;
    }

    if (tid < KNN) {
        const unsigned s = s_sel[tid];
        const float* srow = bank + (size_t)s * DIMD;
        float dot = 0.f;
        for (int d = 0; d < DIMD; ++d) dot += srow[d] * xv[d];
        float d2 = x2[b * PPB + nstar] + y2[s] - 2.0f * dot;
        s_dist[tid] = sqrtf(fmaxf(d2, EPSF));
    }
    __syncthreads();

    if (tid == 0) {
        float mx = s_dist[0];
        for (int i = 1; i < KNN; ++i) mx = fmaxf(mx, s_dist[i]);
        float sum = 0.f, e0 = 0.f;
        for (int i = 0; i < KNN; ++i) {
            float e = expf(s_dist[i] - mx);
            sum += e;
            if (i == 0) e0 = e;
        }
        float w = 1.0f - e0 / sum;
        out[b] = w * sqrtf(fmaxf(d2star, EPSF));
    }
}

extern "C" void kernel_launch(void* const* d_in, const int* in_sizes, int n_in,
                              void* d_out, int out_size, void* d_ws, size_t ws_size,
                              hipStream_t stream) {
    const float* emb  = (const float*)d_in[0];
    const float* bank = (const float*)d_in[1];
    float* out = (float*)d_out;

    char* ws = (char*)d_ws;
    u64*      packed = (u64*)      (ws + 0);         //  50176 B
    float*    x2     = (float*)    (ws + 65536);     //  25088 B
    float*    y2     = (float*)    (ws + 131072);    //  65536 B
    uint4*    binfo  = (uint4*)    (ws + 200704);    //    128 B
    float*    dnn    = (float*)    (ws + 262144);    // 524288 B
    _Float16* GAh    = (_Float16*) (ws + 786432);    // 1605632 B
    _Float16* GBh    = (_Float16*) (ws + 2392064);   // 4194304 B  (end 6586368)

    {
        const int rows = M_BANK + N_EMB;             // 22656
        const int blocks = rows * 16 / 256;          // 1416
        convert_kernel<<<blocks, 256, 0, stream>>>(emb, bank, GAh, GBh, x2, y2, packed);
    }

    dist_min_mfma<<<49 * 16, 256, 0, stream>>>(GAh, GBh, x2, y2, packed);

    argmax_kernel<<<BATCH, 256, 0, stream>>>(packed, emb, bank, x2, y2, binfo);

    dnn_kernel<<<dim3(M_BANK / 256, BATCH), 256, 0, stream>>>(bank, y2, binfo, dnn);

    final_kernel<<<BATCH, 256, 0, stream>>>(emb, bank, x2, y2, binfo, dnn, out);
}